// Round 3
// baseline (358.278 us; speedup 1.0000x reference)
//
#include <hip/hip_runtime.h>
#include <cmath>

#define BATCH 128
#define KDIM 1024
#define VOCAB 32001
#define G3 3072
#define GIP_STRIDE (BATCH * G3)   // 393216 floats per split-K partial

typedef __bf16 bf16_t;
typedef bf16_t bf16x8 __attribute__((ext_vector_type(8)));
typedef float f32x4 __attribute__((ext_vector_type(4)));

// ---------------- async global->LDS (16B/lane, wave-uniform LDS base) --------
__device__ __forceinline__ void stage16(const float* g, void* lds_wave_base) {
    __builtin_amdgcn_global_load_lds(
        (const __attribute__((address_space(1))) void*)g,
        (__attribute__((address_space(3))) void*)lds_wave_base, 16, 0, 0);
}

// Read one MFMA fragment (8 bf16 along K) from an LDS fp32 tile [rows][32],
// granule-XOR swizzled: physical granule = logical ^ (row&7). Optional ReLU.
template<bool RELU>
__device__ __forceinline__ bf16x8 frag_from_lds(const float* s, int row, int quad) {
    const int s7 = row & 7;
    f32x4 u = *(const f32x4*)(s + row * 32 + (((2 * quad) ^ s7) * 4));
    f32x4 v = *(const f32x4*)(s + row * 32 + (((2 * quad + 1) ^ s7) * 4));
    if (RELU) {
#pragma unroll
        for (int k = 0; k < 4; ++k) { u[k] = fmaxf(u[k], 0.f); v[k] = fmaxf(v[k], 0.f); }
    }
    bf16x8 r;
    r[0] = (bf16_t)u[0]; r[1] = (bf16_t)u[1]; r[2] = (bf16_t)u[2]; r[3] = (bf16_t)u[3];
    r[4] = (bf16_t)v[0]; r[5] = (bf16_t)v[1]; r[6] = (bf16_t)v[2]; r[7] = (bf16_t)v[3];
    return r;
}

// ---------------- BM=128 double-buffered GEMM core ---------------------------
// C[0:128, n0:n0+64] = A[128,1024] (rows gathered via idx if GATHER, +ReLU)
//                      * W[Wrows,1024]^T (+bias).  256 thr = 4 waves;
// wave (wm=wave&1, wn=wave>>1) computes rows wm*64..+63, cols n0+wn*32..+31.
template<bool GATHER>
__device__ __forceinline__ void gemm128_core(
    const float* __restrict__ Abase, const int* __restrict__ idx,
    const float* __restrict__ W, const float* __restrict__ bias,
    float* __restrict__ C, int ldc, int Wrows, int n0, int kbeg, int kend)
{
    __shared__ float sA[2][128 * 32];
    __shared__ float sB[2][64 * 32];
    const int t    = threadIdx.x;
    const int wave = t >> 6;
    const int lane = t & 63;
    const int l15  = lane & 15;
    const int quad = lane >> 4;
    const int wm   = wave & 1;
    const int wn   = wave >> 1;
    const int srow = t >> 3;          // staging: row within 32-row round
    const int sg   = t & 7;           // staging: physical granule

    // Per-thread staging source pointers (fixed row + swizzled granule)
    const float* aSrc[4];
#pragma unroll
    for (int r = 0; r < 4; ++r) {
        const int row = r * 32 + srow;
        const int kg  = sg ^ (row & 7);
        const float* rb = GATHER ? Abase + (size_t)idx[row] * KDIM
                                 : Abase + (size_t)row * KDIM;
        aSrc[r] = rb + kg * 4;
    }
    const float* wSrc[2];
#pragma unroll
    for (int r = 0; r < 2; ++r) {
        const int row = r * 32 + srow;
        int wr = n0 + row; if (wr > Wrows - 1) wr = Wrows - 1;
        wSrc[r] = W + (size_t)wr * KDIM + (sg ^ (row & 7)) * 4;
    }

    auto issue = [&](int k0, int buf) {
#pragma unroll
        for (int r = 0; r < 4; ++r)
            stage16(aSrc[r] + k0, (char*)&sA[buf][0] + r * 4096 + wave * 1024);
#pragma unroll
        for (int r = 0; r < 2; ++r)
            stage16(wSrc[r] + k0, (char*)&sB[buf][0] + r * 4096 + wave * 1024);
    };

    f32x4 acc[4][2];
#pragma unroll
    for (int i = 0; i < 4; ++i)
#pragma unroll
        for (int j = 0; j < 2; ++j) acc[i][j] = f32x4{0.f, 0.f, 0.f, 0.f};

    issue(kbeg, 0);
    __syncthreads();                  // stage 0 landed
    int buf = 0;
    for (int k0 = kbeg; k0 < kend; k0 += 32) {
        if (k0 + 32 < kend) issue(k0 + 32, buf ^ 1);   // prefetch next stage
        bf16x8 bf[2];
#pragma unroll
        for (int j = 0; j < 2; ++j)
            bf[j] = frag_from_lds<false>(&sB[buf][0], wn * 32 + j * 16 + l15, quad);
#pragma unroll
        for (int i = 0; i < 4; ++i) {
            const bf16x8 af =
                frag_from_lds<GATHER>(&sA[buf][0], wm * 64 + i * 16 + l15, quad);
#pragma unroll
            for (int j = 0; j < 2; ++j)
                acc[i][j] = __builtin_amdgcn_mfma_f32_16x16x32_bf16(
                    af, bf[j], acc[i][j], 0, 0, 0);
        }
        buf ^= 1;
        __syncthreads();              // next stage landed + this buf free
    }

#pragma unroll
    for (int j = 0; j < 2; ++j) {
        const int col = n0 + wn * 32 + j * 16 + l15;
        if (col < Wrows) {
            const float bv = bias ? bias[col] : 0.f;
#pragma unroll
            for (int i = 0; i < 4; ++i)
#pragma unroll
                for (int r = 0; r < 4; ++r) {
                    const int row = wm * 64 + i * 16 + quad * 4 + r;
                    C[(size_t)row * ldc + col] = acc[i][j][r] + bv;
                }
        }
    }
}

// Layer 0: z=0 gathers relu(emb[idx]) * w_ih^T; z=1 plain hidden * w_hh^T
__global__ __launch_bounds__(256) void gemm_gru0(
    const int* __restrict__ idx, const float* __restrict__ emb,
    const float* __restrict__ wih, float* __restrict__ giP,
    const float* __restrict__ hprev, const float* __restrict__ whh,
    float* __restrict__ ghP)
{
    const int split = blockIdx.x;
    const int n0    = blockIdx.y * 64;
    const int kbeg  = split * 256;
    if (blockIdx.z == 0)
        gemm128_core<true>(emb, idx, wih, nullptr, giP + (size_t)split * GIP_STRIDE,
                           G3, G3, n0, kbeg, kbeg + 256);
    else
        gemm128_core<false>(hprev, nullptr, whh, nullptr,
                            ghP + (size_t)split * GIP_STRIDE, G3, G3, n0, kbeg, kbeg + 256);
}

// Layer 1: both operands plain
__global__ __launch_bounds__(256) void gemm_gru1(
    const float* __restrict__ h0, const float* __restrict__ wih,
    float* __restrict__ giP, const float* __restrict__ hprev,
    const float* __restrict__ whh, float* __restrict__ ghP)
{
    const int split = blockIdx.x;
    const int n0    = blockIdx.y * 64;
    const int kbeg  = split * 256;
    if (blockIdx.z == 0)
        gemm128_core<false>(h0, nullptr, wih, nullptr,
                            giP + (size_t)split * GIP_STRIDE, G3, G3, n0, kbeg, kbeg + 256);
    else
        gemm128_core<false>(hprev, nullptr, whh, nullptr,
                            ghP + (size_t)split * GIP_STRIDE, G3, G3, n0, kbeg, kbeg + 256);
}

// Vocab projection: 501 blocks, W streamed from HBM exactly once
__global__ __launch_bounds__(256) void gemm_vocab(
    const float* __restrict__ A, const float* __restrict__ W,
    const float* __restrict__ bias, float* __restrict__ C)
{
    gemm128_core<false>(A, nullptr, W, bias, C, VOCAB, VOCAB,
                        blockIdx.x * 64, 0, KDIM);
}

// ---------------- gate: sum 4 split-K partials + biases + GRU math -----------
__device__ __forceinline__ f32x4 sum_splits(const float* p) {
    f32x4 s = *(const f32x4*)p;
    s += *(const f32x4*)(p + GIP_STRIDE);
    s += *(const f32x4*)(p + 2 * GIP_STRIDE);
    s += *(const f32x4*)(p + 3 * GIP_STRIDE);
    return s;
}

__global__ __launch_bounds__(256) void gru_gate(const float* __restrict__ giP,
                                                const float* __restrict__ ghP,
                                                const float* __restrict__ b_ih,
                                                const float* __restrict__ b_hh,
                                                const float* __restrict__ hprev,
                                                float* __restrict__ hout) {
    const int i  = blockIdx.x * 256 + threadIdx.x;  // 0..32767
    const int b  = i >> 8;
    const int j  = (i & 255) * 4;
    const size_t base = (size_t)b * G3 + j;

    f32x4 ir = sum_splits(giP + base),        hr = sum_splits(ghP + base);
    f32x4 iz = sum_splits(giP + base + 1024), hz = sum_splits(ghP + base + 1024);
    f32x4 in = sum_splits(giP + base + 2048), hn = sum_splits(ghP + base + 2048);
    const f32x4 bir = *(const f32x4*)(b_ih + j);
    const f32x4 biz = *(const f32x4*)(b_ih + j + 1024);
    const f32x4 bin = *(const f32x4*)(b_ih + j + 2048);
    const f32x4 bhr = *(const f32x4*)(b_hh + j);
    const f32x4 bhz = *(const f32x4*)(b_hh + j + 1024);
    const f32x4 bhn = *(const f32x4*)(b_hh + j + 2048);
    const f32x4 hp  = *(const f32x4*)(hprev + (size_t)b * KDIM + j);

    f32x4 o;
#pragma unroll
    for (int k = 0; k < 4; ++k) {
        const float r = 1.f / (1.f + __expf(-(ir[k] + bir[k] + hr[k] + bhr[k])));
        const float z = 1.f / (1.f + __expf(-(iz[k] + biz[k] + hz[k] + bhz[k])));
        const float a = in[k] + bin[k] + r * (hn[k] + bhn[k]);
        const float n = 1.f - 2.f / (__expf(2.f * a) + 1.f);   // tanh
        o[k] = (1.f - z) * n + z * hp[k];
    }
    *(f32x4*)(hout + (size_t)b * KDIM + j) = o;
}

// ---------------- online log-softmax: one read pass (m,s), one write pass ----
__global__ __launch_bounds__(1024) void log_softmax_rows(float* __restrict__ out) {
    float* row = out + (size_t)blockIdx.x * VOCAB;
    const int t = threadIdx.x;
    __shared__ float sm[16], ss[16];

    float m = -3.4e38f, s = 0.f;
    for (int i = t; i < VOCAB; i += 1024) {
        const float v  = row[i];
        const float mn = fmaxf(m, v);
        s = s * __expf(m - mn) + __expf(v - mn);
        m = mn;
    }
#pragma unroll
    for (int o = 32; o; o >>= 1) {
        const float mo = __shfl_down(m, o);
        const float so = __shfl_down(s, o);
        const float mn = fmaxf(m, mo);
        s = s * __expf(m - mn) + so * __expf(mo - mn);
        m = mn;
    }
    if ((t & 63) == 0) { sm[t >> 6] = m; ss[t >> 6] = s; }
    __syncthreads();
    if (t == 0) {
        float M = sm[0], S = ss[0];
#pragma unroll
        for (int w = 1; w < 16; ++w) {
            const float mn = fmaxf(M, sm[w]);
            S = S * __expf(M - mn) + ss[w] * __expf(sm[w] - mn);
            M = mn;
        }
        sm[0] = M + __logf(S);
    }
    __syncthreads();
    const float L = sm[0];

    for (int i = t * 4; i + 3 < VOCAB; i += 4096) {
        f32x4 v = *(const f32x4*)(row + i);
        v[0] -= L; v[1] -= L; v[2] -= L; v[3] -= L;
        *(f32x4*)(row + i) = v;
    }
    if (t == 0) row[32000] -= L;
}

// ---------------- launch -----------------------------------------------------
extern "C" void kernel_launch(void* const* d_in, const int* in_sizes, int n_in,
                              void* d_out, int out_size, void* d_ws, size_t ws_size,
                              hipStream_t stream) {
    const int*   ivec  = (const int*)  d_in[0];
    const float* hidden= (const float*)d_in[1];
    const float* emb   = (const float*)d_in[2];
    const float* w_ih0 = (const float*)d_in[3];
    const float* w_hh0 = (const float*)d_in[4];
    const float* b_ih0 = (const float*)d_in[5];
    const float* b_hh0 = (const float*)d_in[6];
    const float* w_ih1 = (const float*)d_in[7];
    const float* w_hh1 = (const float*)d_in[8];
    const float* b_ih1 = (const float*)d_in[9];
    const float* b_hh1 = (const float*)d_in[10];
    const float* w_out = (const float*)d_in[11];
    const float* b_out = (const float*)d_in[12];

    float* out = (float*)d_out;
    float* h0  = out + (size_t)BATCH * VOCAB;   // hidden_out[0]
    float* h1  = h0 + BATCH * KDIM;             // hidden_out[1]

    // Scratch inside logits region (fully overwritten by vocab GEMM):
    float* giP = out + 131072;                  // [4][128][3072]
    float* ghP = giP + 4 * GIP_STRIDE;          // [4][128][3072]  (ends 3276800 < 4096128)

    const float* hprev0 = hidden;
    const float* hprev1 = hidden + BATCH * KDIM;

    gemm_gru0<<<dim3(4, 48, 2), 256, 0, stream>>>(ivec, emb, w_ih0, giP,
                                                  hprev0, w_hh0, ghP);
    gru_gate<<<128, 256, 0, stream>>>(giP, ghP, b_ih0, b_hh0, hprev0, h0);

    gemm_gru1<<<dim3(4, 48, 2), 256, 0, stream>>>(h0, w_ih1, giP,
                                                  hprev1, w_hh1, ghP);
    gru_gate<<<128, 256, 0, stream>>>(giP, ghP, b_ih1, b_hh1, hprev1, h1);

    gemm_vocab<<<501, 256, 0, stream>>>(h1, w_out, b_out, out);

    log_softmax_rows<<<128, 1024, 0, stream>>>(out);
}

// Round 4
// 336.622 us; speedup vs baseline: 1.0643x; 1.0643x over previous
//
#include <hip/hip_runtime.h>
#include <cmath>

#define BATCH 128
#define KDIM 1024
#define VOCAB 32001
#define G3 3072
#define GIP_STRIDE (BATCH * G3)   // floats per split-K partial

typedef __bf16 bf16_t;
typedef bf16_t bf16x8 __attribute__((ext_vector_type(8)));
typedef float f32x4 __attribute__((ext_vector_type(4)));

// ---------------- async global->LDS (16B/lane, lanes contiguous per wave) ----
__device__ __forceinline__ void stage16(const void* g, void* lds) {
    __builtin_amdgcn_global_load_lds(
        (const __attribute__((address_space(1))) void*)g,
        (__attribute__((address_space(3))) void*)lds, 16, 0, 0);
}

// ---------------- GEMM core ---------------------------------------------------
// C[0:128, n0:n0+64] = A_bf16[128,1024] * W_f32[Wrows,1024]^T (+bias)
// BK=64/stage, single-buffered LDS, 256 thr = 4 waves.
// Wave (wm=wave&1, wn=wave>>1): rows wm*64..+63, cols n0+wn*32..+31.
// sA: bf16 [128][64], row=128B=8 granules, phys granule = g ^ (row&7)
// sB: f32  [64][64],  row=256B=16 granules, phys granule = g ^ (row&15)
template<bool BIAS>
__device__ __forceinline__ void gemm_core(
    const bf16_t* __restrict__ A, const float* __restrict__ W,
    const float* __restrict__ bias, float* __restrict__ C,
    int ldc, int Wrows, int n0, int kbeg, int kend)
{
    __shared__ bf16_t sA[128 * 64];   // 16 KB
    __shared__ float  sB[64 * 64];    // 16 KB
    const int t    = threadIdx.x;
    const int wave = t >> 6;
    const int lane = t & 63;
    const int l15  = lane & 15;
    const int quad = lane >> 4;
    const int wm   = wave & 1;
    const int wn   = wave >> 1;

    // -------- staging maps (lane l of wave w lands at uniform_base + l*16) ---
    const bf16_t* aSrc[4]; int aDst[4];
#pragma unroll
    for (int r = 0; r < 4; ++r) {
        const int row = r * 32 + (t >> 3);       // 0..127
        const int sg  = t & 7;
        const int kg  = sg ^ (row & 7);
        aSrc[r] = A + (size_t)row * KDIM + kg * 8 + kbeg;
        aDst[r] = row * 128 + sg * 16;           // bytes
    }
    const float* wSrc[4]; int wDst[4];
#pragma unroll
    for (int r = 0; r < 4; ++r) {
        const int row = r * 16 + (t >> 4);       // 0..63
        int wr = n0 + row; if (wr > Wrows - 1) wr = Wrows - 1;
        const int sg = t & 15;
        const int kg = sg ^ (row & 15);
        wSrc[r] = W + (size_t)wr * KDIM + kg * 4 + kbeg;
        wDst[r] = row * 256 + sg * 16;           // bytes
    }

    f32x4 acc[4][2];
#pragma unroll
    for (int i = 0; i < 4; ++i)
#pragma unroll
        for (int j = 0; j < 2; ++j) acc[i][j] = f32x4{0.f, 0.f, 0.f, 0.f};

    for (int k0 = 0; k0 < kend - kbeg; k0 += 64) {
#pragma unroll
        for (int r = 0; r < 4; ++r) stage16(aSrc[r] + k0, (char*)sA + aDst[r]);
#pragma unroll
        for (int r = 0; r < 4; ++r) stage16(wSrc[r] + k0, (char*)sB + wDst[r]);
        __syncthreads();              // loads landed
#pragma unroll
        for (int s = 0; s < 2; ++s) { // two 32-wide k-steps per stage
            bf16x8 bfr[2];
#pragma unroll
            for (int j = 0; j < 2; ++j) {
                const int row = wn * 32 + j * 16 + l15;
                const int gu  = (s * 8 + 2 * quad) ^ (row & 15);  // logical even granule
                const f32x4 u = *(const f32x4*)((const char*)sB + row * 256 + gu * 16);
                const f32x4 v = *(const f32x4*)((const char*)sB + row * 256 + (gu ^ 1) * 16);
                bf16x8 b;
                b[0] = (bf16_t)u[0]; b[1] = (bf16_t)u[1]; b[2] = (bf16_t)u[2]; b[3] = (bf16_t)u[3];
                b[4] = (bf16_t)v[0]; b[5] = (bf16_t)v[1]; b[6] = (bf16_t)v[2]; b[7] = (bf16_t)v[3];
                bfr[j] = b;
            }
#pragma unroll
            for (int i = 0; i < 4; ++i) {
                const int row  = wm * 64 + i * 16 + l15;
                const int phys = (s * 4 + quad) ^ (row & 7);
                const bf16x8 af = *(const bf16x8*)((const char*)sA + row * 128 + phys * 16);
#pragma unroll
                for (int j = 0; j < 2; ++j)
                    acc[i][j] = __builtin_amdgcn_mfma_f32_16x16x32_bf16(
                        af, bfr[j], acc[i][j], 0, 0, 0);
            }
        }
        __syncthreads();              // safe to overwrite tiles
    }

#pragma unroll
    for (int j = 0; j < 2; ++j) {
        const int col = n0 + wn * 32 + j * 16 + l15;
        if (col < Wrows) {
            const float bv = BIAS ? bias[col] : 0.f;
#pragma unroll
            for (int i = 0; i < 4; ++i)
#pragma unroll
                for (int r = 0; r < 4; ++r) {
                    const int row = wm * 64 + i * 16 + quad * 4 + r;
                    C[(size_t)row * ldc + col] = acc[i][j][r] + bv;
                }
        }
    }
}

// GRU dual GEMM, split-K=4 (256 K each), giP/ghP fp32 partials [4][128][3072]
__global__ __launch_bounds__(256, 4) void gemm_gru(
    const bf16_t* __restrict__ Ai, const float* __restrict__ wih,
    float* __restrict__ giP,
    const bf16_t* __restrict__ Ah, const float* __restrict__ whh,
    float* __restrict__ ghP)
{
    const int split = blockIdx.x;
    const int n0    = blockIdx.y * 64;
    const int kbeg  = split * 256;
    if (blockIdx.z == 0)
        gemm_core<false>(Ai, wih, nullptr, giP + (size_t)split * GIP_STRIDE,
                         G3, G3, n0, kbeg, kbeg + 256);
    else
        gemm_core<false>(Ah, whh, nullptr, ghP + (size_t)split * GIP_STRIDE,
                         G3, G3, n0, kbeg, kbeg + 256);
}

// Vocab projection: 501 blocks, W streamed from HBM exactly once
__global__ __launch_bounds__(256, 4) void gemm_vocab(
    const bf16_t* __restrict__ A, const float* __restrict__ W,
    const float* __restrict__ bias, float* __restrict__ C)
{
    gemm_core<true>(A, W, bias, C, VOCAB, VOCAB, blockIdx.x * 64, 0, KDIM);
}

// ---------------- prep: x=relu(emb[idx]) -> bf16; hidden[0/1] -> bf16 --------
// dst layout: xb | hp0b | hp1b contiguous (3 * 131072 bf16)
__global__ __launch_bounds__(256) void prep_bf16(const int* __restrict__ idx,
                                                 const float* __restrict__ emb,
                                                 const float* __restrict__ hidden,
                                                 bf16_t* __restrict__ dst) {
    const int i = blockIdx.x * 256 + threadIdx.x;   // 0..98303 (x4 floats)
    const int sec = i >> 15;                        // 0:x 1:hp0 2:hp1
    const int j   = i & 32767;
    f32x4 v;
    if (sec == 0) {
        const int b = j >> 8, e4 = j & 255;
        v = ((const f32x4*)(emb + (size_t)idx[b] * KDIM))[e4];
#pragma unroll
        for (int k = 0; k < 4; ++k) v[k] = fmaxf(v[k], 0.f);
    } else {
        v = ((const f32x4*)(hidden + (size_t)(sec - 1) * (BATCH * KDIM)))[j];
    }
    bf16_t o[4];
#pragma unroll
    for (int k = 0; k < 4; ++k) o[k] = (bf16_t)v[k];
    *(uint64_t*)(dst + (size_t)i * 4) = *(const uint64_t*)o;
}

// ---------------- gate: sum 4 split-K partials + biases + GRU math -----------
__device__ __forceinline__ f32x4 sum_splits(const float* p) {
    f32x4 s = *(const f32x4*)p;
    s += *(const f32x4*)(p + GIP_STRIDE);
    s += *(const f32x4*)(p + 2 * GIP_STRIDE);
    s += *(const f32x4*)(p + 3 * GIP_STRIDE);
    return s;
}

__global__ __launch_bounds__(256) void gru_gate(const float* __restrict__ giP,
                                                const float* __restrict__ ghP,
                                                const float* __restrict__ b_ih,
                                                const float* __restrict__ b_hh,
                                                const float* __restrict__ hprev,
                                                float* __restrict__ hout,
                                                bf16_t* __restrict__ hout_bf16) {
    const int i  = blockIdx.x * 256 + threadIdx.x;  // 0..32767
    const int b  = i >> 8;
    const int j  = (i & 255) * 4;
    const size_t base = (size_t)b * G3 + j;

    f32x4 ir = sum_splits(giP + base),        hr = sum_splits(ghP + base);
    f32x4 iz = sum_splits(giP + base + 1024), hz = sum_splits(ghP + base + 1024);
    f32x4 in = sum_splits(giP + base + 2048), hn = sum_splits(ghP + base + 2048);
    const f32x4 bir = *(const f32x4*)(b_ih + j);
    const f32x4 biz = *(const f32x4*)(b_ih + j + 1024);
    const f32x4 bin = *(const f32x4*)(b_ih + j + 2048);
    const f32x4 bhr = *(const f32x4*)(b_hh + j);
    const f32x4 bhz = *(const f32x4*)(b_hh + j + 1024);
    const f32x4 bhn = *(const f32x4*)(b_hh + j + 2048);
    const f32x4 hp  = *(const f32x4*)(hprev + (size_t)b * KDIM + j);

    f32x4 o;
    bf16_t ob[4];
#pragma unroll
    for (int k = 0; k < 4; ++k) {
        const float r = 1.f / (1.f + __expf(-(ir[k] + bir[k] + hr[k] + bhr[k])));
        const float z = 1.f / (1.f + __expf(-(iz[k] + biz[k] + hz[k] + bhz[k])));
        const float a = in[k] + bin[k] + r * (hn[k] + bhn[k]);
        const float n = 1.f - 2.f / (__expf(2.f * a) + 1.f);   // tanh
        o[k] = (1.f - z) * n + z * hp[k];
        ob[k] = (bf16_t)o[k];
    }
    *(f32x4*)(hout + (size_t)b * KDIM + j) = o;
    *(uint64_t*)(hout_bf16 + (size_t)b * KDIM + j) = *(const uint64_t*)ob;
}

// ---------------- online log-softmax: one read pass (m,s), one write pass ----
__global__ __launch_bounds__(1024) void log_softmax_rows(float* __restrict__ out) {
    float* row = out + (size_t)blockIdx.x * VOCAB;
    const int t = threadIdx.x;
    __shared__ float sm[16], ss[16];

    float m = -3.4e38f, s = 0.f;
    for (int i = t; i < VOCAB; i += 1024) {
        const float v  = row[i];
        const float mn = fmaxf(m, v);
        s = s * __expf(m - mn) + __expf(v - mn);
        m = mn;
    }
#pragma unroll
    for (int o = 32; o; o >>= 1) {
        const float mo = __shfl_down(m, o);
        const float so = __shfl_down(s, o);
        const float mn = fmaxf(m, mo);
        s = s * __expf(m - mn) + so * __expf(mo - mn);
        m = mn;
    }
    if ((t & 63) == 0) { sm[t >> 6] = m; ss[t >> 6] = s; }
    __syncthreads();
    if (t == 0) {
        float M = sm[0], S = ss[0];
#pragma unroll
        for (int w = 1; w < 16; ++w) {
            const float mn = fmaxf(M, sm[w]);
            S = S * __expf(M - mn) + ss[w] * __expf(sm[w] - mn);
            M = mn;
        }
        sm[0] = M + __logf(S);
    }
    __syncthreads();
    const float L = sm[0];

    for (int i = t * 4; i + 3 < VOCAB; i += 4096) {
        f32x4 v = *(const f32x4*)(row + i);
        v[0] -= L; v[1] -= L; v[2] -= L; v[3] -= L;
        *(f32x4*)(row + i) = v;
    }
    if (t == 0) row[32000] -= L;
}

// ---------------- launch -----------------------------------------------------
extern "C" void kernel_launch(void* const* d_in, const int* in_sizes, int n_in,
                              void* d_out, int out_size, void* d_ws, size_t ws_size,
                              hipStream_t stream) {
    const int*   ivec  = (const int*)  d_in[0];
    const float* hidden= (const float*)d_in[1];
    const float* emb   = (const float*)d_in[2];
    const float* w_ih0 = (const float*)d_in[3];
    const float* w_hh0 = (const float*)d_in[4];
    const float* b_ih0 = (const float*)d_in[5];
    const float* b_hh0 = (const float*)d_in[6];
    const float* w_ih1 = (const float*)d_in[7];
    const float* w_hh1 = (const float*)d_in[8];
    const float* b_ih1 = (const float*)d_in[9];
    const float* b_hh1 = (const float*)d_in[10];
    const float* w_out = (const float*)d_in[11];
    const float* b_out = (const float*)d_in[12];

    float* out = (float*)d_out;
    float* h0  = out + (size_t)BATCH * VOCAB;   // hidden_out[0] (fp32)
    float* h1  = h0 + BATCH * KDIM;             // hidden_out[1] (fp32)

    // All scratch in d_ws (≥ 14 MB needed; ws is much larger)
    float*  ws   = (float*)d_ws;
    float*  giP  = ws;                          // [4][128][3072] fp32
    float*  ghP  = ws + 4 * (size_t)GIP_STRIDE; // [4][128][3072] fp32
    bf16_t* xb   = (bf16_t*)(ws + 8 * (size_t)GIP_STRIDE);
    bf16_t* hp0b = xb   + BATCH * KDIM;
    bf16_t* hp1b = hp0b + BATCH * KDIM;
    bf16_t* h0b  = hp1b + BATCH * KDIM;
    bf16_t* h1b  = h0b  + BATCH * KDIM;

    const float* hprev0 = hidden;
    const float* hprev1 = hidden + BATCH * KDIM;

    prep_bf16<<<384, 256, 0, stream>>>(ivec, emb, hidden, xb);

    gemm_gru<<<dim3(4, 48, 2), 256, 0, stream>>>(xb, w_ih0, giP, hp0b, w_hh0, ghP);
    gru_gate<<<128, 256, 0, stream>>>(giP, ghP, b_ih0, b_hh0, hprev0, h0, h0b);

    gemm_gru<<<dim3(4, 48, 2), 256, 0, stream>>>(h0b, w_ih1, giP, hp1b, w_hh1, ghP);
    gru_gate<<<128, 256, 0, stream>>>(giP, ghP, b_ih1, b_hh1, hprev1, h1, h1b);

    gemm_vocab<<<501, 256, 0, stream>>>(h1b, w_out, b_out, out);

    log_softmax_rows<<<128, 1024, 0, stream>>>(out);
}